// Round 17
// baseline (188.928 us; speedup 1.0000x reference)
//
#include <hip/hip_runtime.h>
#include <stdint.h>

// Dims
#define NB 64
#define NL 64
#define NC 32
#define NK 100
#define NH 8
#define DKEY 16
#define DM 128
#define NG 128       // H*DKEY
#define DLLM 768
#define KP 4128      // 4096 + 32 (probs tail) : wout row stride
#define TEMP 0.25f   // 1/sqrt(16)
#define QSCL 0.3606737602222409f   // TEMP * log2(e): folded into Q so P = exp2(S)

typedef __attribute__((ext_vector_type(8))) short bf16x8;
typedef __attribute__((ext_vector_type(4))) short bf16x4;
typedef __attribute__((ext_vector_type(4))) float f32x4;

typedef uint32_t __attribute__((address_space(1))) gu32;
typedef uint32_t __attribute__((address_space(3))) lu32;

__device__ __forceinline__ void gload_lds16(const void* g, void* l) {
    __builtin_amdgcn_global_load_lds((const gu32*)g, (lu32*)l, 16, 0, 0);
}

// ---------- bf16 helpers ----------
__device__ __forceinline__ uint16_t f2bf(float f) {
    union { float f; uint32_t i; } x; x.f = f;
    uint32_t r = x.i + 0x7FFFu + ((x.i >> 16) & 1u);
    return (uint16_t)(r >> 16);
}
__device__ __forceinline__ uint32_t pack2(float lo, float hi) {
    return (uint32_t)f2bf(lo) | ((uint32_t)f2bf(hi) << 16);
}
__device__ __forceinline__ uint32_t cvtpk_bf16(float lo, float hi) {
    uint32_t r;
    asm("v_cvt_pk_bf16_f32 %0, %1, %2" : "=v"(r) : "v"(lo), "v"(hi));
    return r;
}
// Bare v_exp_f32 (2^x): logits bounded |x| <~ 6, so the raw transcendental
// is safe (the ~6-op correctly-rounded __builtin_exp2f expansion is not needed).
__device__ __forceinline__ float fexp2(float x) {
    float r;
    asm("v_exp_f32 %0, %1" : "=v"(r) : "v"(x));
    return r;
}

// ---------------------------------------------------------------------------
// Kernel 0: merged conversions.
// ---------------------------------------------------------------------------
__global__ __launch_bounds__(256) void convert_all_kernel(
    const float* __restrict__ ts,
    const float* __restrict__ Wq,
    const float* __restrict__ topk,
    const float* __restrict__ Wk,
    const float* __restrict__ Wv,
    const float* __restrict__ Wo,
    const float* __restrict__ bo,
    uint16_t* __restrict__ tsbf,
    uint16_t* __restrict__ wqbf,
    uint16_t* __restrict__ topkbf,
    uint16_t* __restrict__ wkbf,
    uint16_t* __restrict__ wvbf,
    uint16_t* __restrict__ wobt)
{
    __shared__ float tile[32][65];
    int bid = blockIdx.x;
    int t = threadIdx.x;

    if (bid < 4096) {
        int i = bid * 256 + t;
        if (i < 524288) {
            tsbf[i] = f2bf(ts[i]);
        } else {
            int j = i - 524288;
            wqbf[j] = f2bf(Wq[(j >> 7) * 129 + (j & 127)]);
        }
    } else if (bid < 15488) {
        int r = bid - 4096;
        if (r < 3200) {
            if (t < 192) {
                float4 v = *(const float4*)(topk + (size_t)r * 768 + t * 4);
                uint2 u;
                u.x = pack2(v.x, v.y);
                u.y = pack2(v.z, v.w);
                *(uint2*)(topkbf + (size_t)r * 768 + t * 4) = u;
            }
        } else {
            int rr = r - 3200;
            const float* src;
            uint16_t* dst;
            if (rr < 4096) {
                src = Wk + (size_t)rr * 769;
                dst = wkbf + (size_t)rr * 768;
            } else {
                rr -= 4096;
                src = Wv + (size_t)rr * 769;
                dst = wvbf + (size_t)rr * 768;
            }
#pragma unroll
            for (int i = 0; i < 3; ++i)
                dst[t + 256 * i] = f2bf(src[t + 256 * i]);
        }
    } else {
        int b2 = bid - 15488;
        int kt = b2 / 12;
        int nb = b2 % 12;
        {
            int rr = t >> 3;
            int c0 = (t & 7) * 8;
            int kg = kt * 32 + rr;
            const float* src = (kg < 4096 ? Wo + (size_t)kg * DLLM
                                          : bo + (size_t)(kg - 4096) * DLLM)
                               + nb * 64 + c0;
            float4 v0 = *(const float4*)src;
            float4 v1 = *(const float4*)(src + 4);
            tile[rr][c0 + 0] = v0.x; tile[rr][c0 + 1] = v0.y;
            tile[rr][c0 + 2] = v0.z; tile[rr][c0 + 3] = v0.w;
            tile[rr][c0 + 4] = v1.x; tile[rr][c0 + 5] = v1.y;
            tile[rr][c0 + 6] = v1.z; tile[rr][c0 + 7] = v1.w;
        }
        __syncthreads();
        {
            int n  = t >> 2;
            int k0 = (t & 3) * 8;
            uint4 u;
            u.x = pack2(tile[k0 + 0][n], tile[k0 + 1][n]);
            u.y = pack2(tile[k0 + 2][n], tile[k0 + 3][n]);
            u.z = pack2(tile[k0 + 4][n], tile[k0 + 5][n]);
            u.w = pack2(tile[k0 + 6][n], tile[k0 + 7][n]);
            *(uint4*)&wobt[((size_t)(nb * 64 + n)) * KP + kt * 32 + k0] = u;
        }
    }
}

// ---------------------------------------------------------------------------
// Kernel 1+2 merged: K/V projection (blocks 0..255) + Q projection
// (blocks 256..1279). Unchanged from round 16.
// ---------------------------------------------------------------------------
__global__ __launch_bounds__(256) void proj_merged_kernel(
    const uint16_t* __restrict__ topkbf,  // [3200][768]
    const uint16_t* __restrict__ wkbf,    // [32*128][768]
    const uint16_t* __restrict__ wvbf,    // [32*128][768]
    const float* __restrict__ Wk,         // bias col
    const float* __restrict__ Wv,         // bias col
    uint16_t* __restrict__ kbuf,          // [32][112][128]
    uint16_t* __restrict__ vbufT,         // [32][128][128]
    const uint16_t* __restrict__ tsbf,    // [4096][128]
    const uint16_t* __restrict__ wqbf,    // [32][128][128]
    const float* __restrict__ Wq,         // bias col
    uint16_t* __restrict__ qbuf)
{
    __shared__ short As[2][4096];
    __shared__ short Bs[2][4096];

    int tid  = threadIdx.x;
    int lane = tid & 63;
    int w    = tid >> 6;
    int wr   = w >> 1;
    int wc   = w & 1;

    if (blockIdx.x < 256) {
        int bid = blockIdx.x;
        int nb = bid & 1;
        int mb = (bid >> 1) & 1;
        int c  = (bid >> 2) & 31;
        int which = bid >> 7;     // 0=K, 1=V

        int r16  = lane & 15;
        int kp   = lane >> 4;

        int arow = mb * 64 + w * 16 + r16;
        int brow = nb * 64 + w * 16 + r16;
        const uint16_t* aptr;
        const uint16_t* bptr;
        if (which == 0) {
            aptr = topkbf + ((size_t)(c * 100 + arow)) * 768 + kp * 8;
            bptr = wkbf   + ((size_t)(c * 128 + brow)) * 768 + kp * 8;
        } else {
            aptr = wvbf   + ((size_t)(c * 128 + arow)) * 768 + kp * 8;
            bptr = topkbf + ((size_t)(c * 100 + brow)) * 768 + kp * 8;
        }

        short* adst[2] = { &As[0][w * 512], &As[1][w * 512] };
        short* bdst[2] = { &Bs[0][w * 512], &Bs[1][w * 512] };

        f32x4 acc[2][2] = {};

        gload_lds16(aptr, adst[0]);
        gload_lds16(bptr, bdst[0]);
        __syncthreads();

        int cur = 0;
        for (int kt = 0; kt < 24; ++kt) {
            if (kt < 23) {
                gload_lds16(aptr + (kt + 1) * 32, adst[cur ^ 1]);
                gload_lds16(bptr + (kt + 1) * 32, bdst[cur ^ 1]);
            }
            const short* Ab = As[cur];
            const short* Bb = Bs[cur];
            bf16x8 a0 = *(const bf16x8*)(Ab + (wr * 2 + 0) * 512 + lane * 8);
            bf16x8 a1 = *(const bf16x8*)(Ab + (wr * 2 + 1) * 512 + lane * 8);
            bf16x8 b0 = *(const bf16x8*)(Bb + (wc * 2 + 0) * 512 + lane * 8);
            bf16x8 b1 = *(const bf16x8*)(Bb + (wc * 2 + 1) * 512 + lane * 8);
            acc[0][0] = __builtin_amdgcn_mfma_f32_16x16x32_bf16(a0, b0, acc[0][0], 0, 0, 0);
            acc[0][1] = __builtin_amdgcn_mfma_f32_16x16x32_bf16(a0, b1, acc[0][1], 0, 0, 0);
            acc[1][0] = __builtin_amdgcn_mfma_f32_16x16x32_bf16(a1, b0, acc[1][0], 0, 0, 0);
            acc[1][1] = __builtin_amdgcn_mfma_f32_16x16x32_bf16(a1, b1, acc[1][1], 0, 0, 0);
            __syncthreads();
            cur ^= 1;
        }

        int mbase = mb * 64 + wr * 32 + (lane >> 4) * 4;
        int nbase = nb * 64 + wc * 32 + (lane & 15);

        if (which == 0) {
            float bias0 = Wk[((size_t)c * 128 + nbase)      * 769 + 768];
            float bias1 = Wk[((size_t)c * 128 + nbase + 16) * 769 + 768];
#pragma unroll
            for (int fm = 0; fm < 2; ++fm)
#pragma unroll
                for (int r = 0; r < 4; ++r) {
                    int mrow = mbase + fm * 16 + r;
                    if (mrow < 112) {
                        kbuf[((size_t)c * 112 + mrow) * 128 + nbase]      = f2bf(acc[fm][0][r] + bias0);
                        kbuf[((size_t)c * 112 + mrow) * 128 + nbase + 16] = f2bf(acc[fm][1][r] + bias1);
                    }
                }
        } else {
#pragma unroll
            for (int fm = 0; fm < 2; ++fm)
#pragma unroll
                for (int r = 0; r < 4; ++r) {
                    int grow = mbase + fm * 16 + r;
                    float bias = Wv[((size_t)c * 128 + grow) * 769 + 768];
#pragma unroll
                    for (int fn = 0; fn < 2; ++fn) {
                        int ncol = nbase + fn * 16;
                        uint16_t val = (ncol < NK) ? f2bf(acc[fm][fn][r] + bias) : (uint16_t)0;
                        vbufT[((size_t)c * 128 + grow) * 128 + ncol] = val;
                    }
                }
        }
    } else {
        int bid = blockIdx.x - 256;
        int mb = bid & 31;
        int c  = bid >> 5;

        int sg  = tid >> 6;
        int skp = (tid >> 4) & 3;
        int sr  = tid & 15;
        const uint16_t* aptr = tsbf + ((size_t)(mb * 128 + sg * 16 + sr)) * 128 + skp * 8;
        const uint16_t* bptr = wqbf + ((size_t)(c * 128 + sg * 16 + sr)) * 128 + skp * 8;

        short* adst[2] = { &As[0][w * 512], &As[1][w * 512] };
        short* bdst[2] = { &Bs[0][w * 512], &Bs[1][w * 512] };

        f32x4 acc[4][4] = {};

        gload_lds16(aptr, adst[0]);
        gload_lds16(aptr + (size_t)64 * 128, adst[0] + 2048);
        gload_lds16(bptr, bdst[0]);
        gload_lds16(bptr + (size_t)64 * 128, bdst[0] + 2048);
        __syncthreads();

        int cur = 0;
        for (int kt = 0; kt < 4; ++kt) {
            if (kt < 3) {
                const uint16_t* ap = aptr + (kt + 1) * 32;
                const uint16_t* bp = bptr + (kt + 1) * 32;
                gload_lds16(ap, adst[cur ^ 1]);
                gload_lds16(ap + (size_t)64 * 128, adst[cur ^ 1] + 2048);
                gload_lds16(bp, bdst[cur ^ 1]);
                gload_lds16(bp + (size_t)64 * 128, bdst[cur ^ 1] + 2048);
            }
            const short* Ab = As[cur];
            const short* Bb = Bs[cur];
            bf16x8 av[4], bv[4];
#pragma unroll
            for (int m = 0; m < 4; ++m)
                av[m] = *(const bf16x8*)(Ab + (wr * 4 + m) * 512 + lane * 8);
#pragma unroll
            for (int n = 0; n < 4; ++n)
                bv[n] = *(const bf16x8*)(Bb + (wc * 4 + n) * 512 + lane * 8);
#pragma unroll
            for (int m = 0; m < 4; ++m)
#pragma unroll
                for (int n = 0; n < 4; ++n)
                    acc[m][n] = __builtin_amdgcn_mfma_f32_16x16x32_bf16(av[m], bv[n], acc[m][n], 0, 0, 0);
            __syncthreads();
            cur ^= 1;
        }

        int mbase = mb * 128 + wr * 64 + (lane >> 4) * 4;
        int nfix  = wc * 64 + (lane & 15);
#pragma unroll
        for (int n = 0; n < 4; ++n) {
            int ncol = nfix + n * 16;
            float bias = Wq[((size_t)c * 128 + ncol) * 129 + 128];
#pragma unroll
            for (int m = 0; m < 4; ++m)
#pragma unroll
                for (int r = 0; r < 4; ++r)
                    qbuf[((size_t)c * 4096 + mbase + m * 16 + r) * 128 + ncol] =
                        f2bf((acc[m][n][r] + bias) * QSCL);
        }
    }
}

// ---------------------------------------------------------------------------
// Kernel 3: MFMA attention (unchanged from round 12: round-7 structure +
// QSCL fold + bare v_exp_f32). LDS = 64 KiB exactly.
// ---------------------------------------------------------------------------
__global__ __launch_bounds__(256) void attn_mfma_kernel(
    const uint16_t* __restrict__ qbuf,
    const uint16_t* __restrict__ kbuf,
    const uint16_t* __restrict__ vbufT,
    const float* __restrict__ probs,
    uint16_t* __restrict__ wout)
{
    __shared__ short Pl[4][64][128];   // 65536 B == 64 KiB exactly

    int bid = blockIdx.x;
    int c = bid >> 6;
    int b = bid & 63;
    int tid = threadIdx.x;
    int lane = tid & 63;
    int w = tid >> 6;
    int g = lane >> 4;        // 0..3
    int l15 = lane & 15;
    int swz = l15 << 4;       // 16B-block XOR swizzle key

    float pr_tok = probs[((size_t)b * 64 + lane) * NC + c];

    uint8_t* Pb = (uint8_t*)&Pl[w][0][0];
    bf16x8 zf = {};

    for (int hh = 0; hh < 2; ++hh) {
        int h = w * 2 + hh;

        // Q fragments (B-operand): groups 0,1 real (d 0..15), groups 2,3 zero
        bf16x8 qb[4];
#pragma unroll
        for (int nt = 0; nt < 4; ++nt) {
            if (g < 2)
                qb[nt] = *(const bf16x8*)&qbuf[((size_t)c * 4096 + b * 64 + nt * 16 + l15) * 128 + h * 16 + g * 8];
            else
                qb[nt] = zf;
        }

        float psum[4] = {0.f, 0.f, 0.f, 0.f};
#pragma unroll
        for (int mt = 0; mt < 7; ++mt) {
            bf16x8 ka;
            if (g < 2)
                ka = *(const bf16x8*)&kbuf[((size_t)c * 112 + mt * 16 + l15) * 128 + h * 16 + g * 8];
            else
                ka = zf;
            f32x4 s[4];
#pragma unroll
            for (int nt = 0; nt < 4; ++nt)
                s[nt] = __builtin_amdgcn_mfma_f32_16x16x32_bf16(ka, qb[nt], (f32x4){0.f,0.f,0.f,0.f}, 0, 0, 0);
            // rows k = mt*16 + 4g + r ; valid iff k < 100
            bool valid = (mt < 6) || (g == 0);
#pragma unroll
            for (int nt = 0; nt < 4; ++nt) {
                float p0 = valid ? fexp2(s[nt][0]) : 0.f;
                float p1 = valid ? fexp2(s[nt][1]) : 0.f;
                float p2 = valid ? fexp2(s[nt][2]) : 0.f;
                float p3 = valid ? fexp2(s[nt][3]) : 0.f;
                psum[nt] += (p0 + p1) + (p2 + p3);
                union { uint32_t u[2]; bf16x4 v; } pk;
                pk.u[0] = cvtpk_bf16(p0, p1);
                pk.u[1] = cvtpk_bf16(p2, p3);
                int l = nt * 16 + l15;
                *(bf16x4*)(Pb + l * 256 + ((mt * 32 + g * 8) ^ swz)) = pk.v;
            }
        }
        // zero pad P cols 112..127
        {
            bf16x4 z4 = {};
#pragma unroll
            for (int nt = 0; nt < 4; ++nt) {
                int l = nt * 16 + l15;
                *(bf16x4*)(Pb + l * 256 + ((224 + g * 8) ^ swz)) = z4;
            }
        }
        // fence: all P ds_writes visible before PV ds_reads
        __syncthreads();

        // full softmax denominators -> registers (every lane gets all copies)
        float rsum[4];
#pragma unroll
        for (int nt = 0; nt < 4; ++nt) {
            float t = psum[nt];
            t += __shfl_xor(t, 16);
            t += __shfl_xor(t, 32);
            rsum[nt] = __builtin_amdgcn_rcpf(t);   // 1/sum for token nt*16+l15
        }

        // PV: oacc[l-tile] over 4 k-chunks of 32
        f32x4 oacc[4] = {};
#pragma unroll
        for (int ch = 0; ch < 4; ++ch) {
            bf16x8 vb = *(const bf16x8*)&vbufT[((size_t)c * 128 + h * 16 + l15) * 128 + ch * 32 + g * 8];
#pragma unroll
            for (int mt = 0; mt < 4; ++mt) {
                int l = mt * 16 + l15;
                bf16x8 pa = *(const bf16x8*)(Pb + l * 256 + ((ch * 64 + g * 16) ^ swz));
                oacc[mt] = __builtin_amdgcn_mfma_f32_16x16x32_bf16(pa, vb, oacc[mt], 0, 0, 0);
            }
        }
        // epilogue: out[l][d], col d = lane&15, row l = mt*16 + 4g + r
#pragma unroll
        for (int mt = 0; mt < 4; ++mt) {
#pragma unroll
            for (int r = 0; r < 4; ++r) {
                int l = mt * 16 + g * 4 + r;
                float sc = __shfl(pr_tok, l) * __shfl(rsum[mt], g * 4 + r);
                wout[((size_t)b * 64 + l) * KP + c * 128 + h * 16 + l15] =
                    f2bf(oacc[mt][r] * sc);
            }
        }
        // fence: PV ds_reads done before next head's P ds_writes (WAR)
        __syncthreads();
    }
    // probs tail column
    if (tid < 64)
        wout[((size_t)b * 64 + tid) * KP + 4096 + c] = f2bf(pr_tok);
}

// ---------------------------------------------------------------------------
// Kernel 4a (fallback when no workspace slack): [Wo;bo] -> WoBT, after attn.
// ---------------------------------------------------------------------------
__global__ __launch_bounds__(256) void convert_wo_kernel(
    const float* __restrict__ Wo,
    const float* __restrict__ bo,
    uint16_t* __restrict__ wobt)
{
    __shared__ float tile[32][65];
    int bid = blockIdx.x;
    int kt = bid / 12;
    int nb = bid % 12;
    int t = threadIdx.x;
    {
        int rr = t >> 3;
        int c0 = (t & 7) * 8;
        int kg = kt * 32 + rr;
        const float* src = (kg < 4096 ? Wo + (size_t)kg * DLLM
                                      : bo + (size_t)(kg - 4096) * DLLM)
                           + nb * 64 + c0;
        float4 v0 = *(const float4*)src;
        float4 v1 = *(const float4*)(src + 4);
        tile[rr][c0 + 0] = v0.x; tile[rr][c0 + 1] = v0.y;
        tile[rr][c0 + 2] = v0.z; tile[rr][c0 + 3] = v0.w;
        tile[rr][c0 + 4] = v1.x; tile[rr][c0 + 5] = v1.y;
        tile[rr][c0 + 6] = v1.z; tile[rr][c0 + 7] = v1.w;
    }
    __syncthreads();
    {
        int n  = t >> 2;
        int k0 = (t & 3) * 8;
        uint4 u;
        u.x = pack2(tile[k0 + 0][n], tile[k0 + 1][n]);
        u.y = pack2(tile[k0 + 2][n], tile[k0 + 3][n]);
        u.z = pack2(tile[k0 + 4][n], tile[k0 + 5][n]);
        u.w = pack2(tile[k0 + 6][n], tile[k0 + 7][n]);
        *(uint4*)&wobt[((size_t)(nb * 64 + n)) * KP + kt * 32 + k0] = u;
    }
}

// ---------------------------------------------------------------------------
// Kernel 4b: split-K MFMA GEMM, 128x192 tile, grid 256 = EXACTLY 1 block/CU
// (round 17). r12's 384-block grid left 128 CUs running 2 blocks serially --
// the dispatch tail. Geometry: 2h x 32mb x 4nb = 256 blocks; 4 waves 2x2 of
// 64x96 (acc[4][6], 24 MFMA/wave/step); 5 gloads/step (A:2, B:3).
// Fragment-major LDS: staging pass p by wave w lands rowgroup 4p+w at
// (4p+w)*512 -- frag read = rowgroup*512 + lane*8, conflict-free b128.
// LDS 40 KB. h=0: 64 steps; h=1: 65 (k 2048..4127 incl probs tail).
// ---------------------------------------------------------------------------
__global__ __launch_bounds__(256) void fgemm_splitk_kernel(
    const uint16_t* __restrict__ wout,   // A  [4096][4128] bf16
    const uint16_t* __restrict__ wobt,   // B^T [768][4128] bf16
    float* __restrict__ part)            // [2][4096][768] fp32
{
    __shared__ short As[2][4096];   // 128 rows x 32 k
    __shared__ short Bs[2][6144];   // 192 rows x 32 k

    int bid = blockIdx.x;
    int swz = (bid & 7) * 32 + (bid >> 3);   // bijective on [0,256)
    int h  = swz >> 7;                        // k-half
    int rr = swz & 127;
    int mb = rr >> 2;                         // 0..31
    int nb = rr & 3;                          // 0..3

    int tid  = threadIdx.x;
    int lane = tid & 63;
    int w    = tid >> 6;
    int wr   = w >> 1;
    int wc   = w & 1;

    int sg = tid >> 6;
    int skp = (tid >> 4) & 3;
    int sr = tid & 15;
    const uint16_t* aptr = wout + ((size_t)(mb * 128 + sg * 16 + sr)) * KP + h * 2048 + skp * 8;
    const uint16_t* bptr = wobt + ((size_t)(nb * 192 + sg * 16 + sr)) * KP + h * 2048 + skp * 8;

    int nkt = h ? 65 : 64;

    f32x4 acc[4][6] = {};

#define STG(S, BUF)                                                           \
    do {                                                                      \
        short* ad = &As[BUF][w * 512];                                        \
        short* bd = &Bs[BUF][w * 512];                                        \
        const uint16_t* ap = aptr + (size_t)(S) * 32;                         \
        const uint16_t* bp = bptr + (size_t)(S) * 32;                         \
        gload_lds16(ap, ad);                                                  \
        gload_lds16(ap + (size_t)64 * KP, ad + 2048);                         \
        gload_lds16(bp, bd);                                                  \
        gload_lds16(bp + (size_t)64 * KP, bd + 2048);                         \
        gload_lds16(bp + (size_t)128 * KP, bd + 4096);                        \
    } while (0)

    STG(0, 0);
    __syncthreads();

    int cur = 0;
    for (int kt = 0; kt < nkt; ++kt) {
        if (kt + 1 < nkt) STG(kt + 1, cur ^ 1);
        const short* Ab = As[cur];
        const short* Bb = Bs[cur];
        bf16x8 av[4], bv[6];
#pragma unroll
        for (int m = 0; m < 4; ++m)
            av[m] = *(const bf16x8*)(Ab + (wr * 4 + m) * 512 + lane * 8);
#pragma unroll
        for (int n = 0; n < 6; ++n)
            bv[n] = *(const bf16x8*)(Bb + (wc * 6 + n) * 512 + lane * 8);
#pragma unroll
        for (int m = 0; m < 4; ++m)
#pragma unroll
            for (int n = 0; n < 6; ++n)
                acc[m][n] = __builtin_amdgcn_mfma_f32_16x16x32_bf16(av[m], bv[n], acc[m][n], 0, 0, 0);
        __syncthreads();
        cur ^= 1;
    }
#undef STG

    float* P = part + (size_t)h * (4096 * 768);
    int mbase = mb * 128 + wr * 64 + (lane >> 4) * 4;
    int nbase = nb * 192 + wc * 96 + (lane & 15);
#pragma unroll
    for (int m = 0; m < 4; ++m)
#pragma unroll
        for (int n = 0; n < 6; ++n)
#pragma unroll
            for (int r = 0; r < 4; ++r)
                P[(size_t)(mbase + m * 16 + r) * DLLM + nbase + n * 16] =
                    acc[m][n][r];
}

// ---------------------------------------------------------------------------
// Kernel 4c: reduce the two K-half partials into the fp32 output.
// ---------------------------------------------------------------------------
__global__ __launch_bounds__(256) void reduce_out_kernel(
    const float* __restrict__ part,
    float* __restrict__ out)
{
    int i = (blockIdx.x * 256 + threadIdx.x) * 4;
    float4 a = *(const float4*)(part + i);
    float4 b = *(const float4*)(part + 4096 * 768 + i);
    float4 s;
    s.x = a.x + b.x; s.y = a.y + b.y; s.z = a.z + b.z; s.w = a.w + b.w;
    *(float4*)(out + i) = s;
}

// ---------------------------------------------------------------------------
extern "C" void kernel_launch(void* const* d_in, const int* in_sizes, int n_in,
                              void* d_out, int out_size, void* d_ws, size_t ws_size,
                              hipStream_t stream) {
    const float* topk  = (const float*)d_in[0];  // (32,100,768)
    const float* ts    = (const float*)d_in[1];  // (64,64,128)
    const float* probs = (const float*)d_in[2];  // (64,64,32)
    const float* Wq    = (const float*)d_in[3];  // (32,128,129)
    const float* Wk    = (const float*)d_in[4];  // (32,128,769)
    const float* Wv    = (const float*)d_in[5];  // (32,128,769)
    const float* Wo    = (const float*)d_in[6];  // (32,128,768)
    const float* bo    = (const float*)d_in[7];  // (32,768)
    float* out = (float*)d_out;

    // workspace (uint16): kbuf | vbufT | qbuf | wout
    uint16_t* ws    = (uint16_t*)d_ws;
    uint16_t* kbuf  = ws;                          // 32*112*128  = 458752
    uint16_t* vbufT = ws + 458752;                 // 32*128*128  = 524288
    uint16_t* qbuf  = ws + 983040;                 // 32*4096*128 = 16777216
    uint16_t* wout  = ws + 983040 + 16777216;      // 4096*4128   = 16908288
    // overlays inside wout region (all dead before attn writes wout):
    uint16_t* tsbf   = wout;                       // 524288   (dead after proj)
    uint16_t* wqbf   = wout + 524288;              // 524288   (dead after proj)
    uint16_t* topkbf = wout + 1048576;             // 2457600  (dead after proj)
    uint16_t* wkbf   = wout + 1048576 + 2457600;   // 3145728  (dead after proj)
    uint16_t* wvbf   = wout + 1048576 + 2457600 + 3145728;  // 3145728, ends 9797632
    // part overlays qbuf region (dead after attn):
    float* part = (float*)(qbuf + 3170304);        // 2*4096*768 fp32 = 25.2 MB

    // wout ends at short-index 983040+16777216+16908288 = 34,668,544.
    const size_t BASE = 34668544;                  // first free short after wout
    bool slack = ws_size >= (BASE + 3170304) * sizeof(uint16_t);
    uint16_t* wobt = slack ? (ws + BASE) : qbuf;

    int nconv = slack ? 17036 : 15488;
    convert_all_kernel<<<nconv, 256, 0, stream>>>(ts, Wq, topk, Wk, Wv, Wo, bo,
                                                  tsbf, wqbf, topkbf, wkbf, wvbf, wobt);
    proj_merged_kernel<<<1280, 256, 0, stream>>>(topkbf, wkbf, wvbf, Wk, Wv,
                                                 kbuf, vbufT, tsbf, wqbf, Wq, qbuf);
    attn_mfma_kernel<<<2048, 256, 0, stream>>>(qbuf, kbuf, vbufT, probs, wout);
    if (!slack)
        convert_wo_kernel<<<1548, 256, 0, stream>>>(Wo, bo, wobt);
    fgemm_splitk_kernel<<<256, 256, 0, stream>>>(wout, wobt, part);
    reduce_out_kernel<<<3072, 256, 0, stream>>>(part, out);
}

// Round 18
// 152.836 us; speedup vs baseline: 1.2361x; 1.2361x over previous
//
#include <hip/hip_runtime.h>
#include <stdint.h>

// Dims
#define NB 64
#define NL 64
#define NC 32
#define NK 100
#define NH 8
#define DKEY 16
#define DM 128
#define NG 128       // H*DKEY
#define DLLM 768
#define KP 4128      // 4096 + 32 (probs tail) : wout row stride
#define TEMP 0.25f   // 1/sqrt(16)
#define QSCL 0.3606737602222409f   // TEMP * log2(e): folded into Q so P = exp2(S)

typedef __attribute__((ext_vector_type(8))) short bf16x8;
typedef __attribute__((ext_vector_type(4))) short bf16x4;
typedef __attribute__((ext_vector_type(4))) float f32x4;

typedef uint32_t __attribute__((address_space(1))) gu32;
typedef uint32_t __attribute__((address_space(3))) lu32;

__device__ __forceinline__ void gload_lds16(const void* g, void* l) {
    __builtin_amdgcn_global_load_lds((const gu32*)g, (lu32*)l, 16, 0, 0);
}

// ---------- bf16 helpers ----------
__device__ __forceinline__ uint16_t f2bf(float f) {
    union { float f; uint32_t i; } x; x.f = f;
    uint32_t r = x.i + 0x7FFFu + ((x.i >> 16) & 1u);
    return (uint16_t)(r >> 16);
}
__device__ __forceinline__ uint32_t pack2(float lo, float hi) {
    return (uint32_t)f2bf(lo) | ((uint32_t)f2bf(hi) << 16);
}
__device__ __forceinline__ uint32_t cvtpk_bf16(float lo, float hi) {
    uint32_t r;
    asm("v_cvt_pk_bf16_f32 %0, %1, %2" : "=v"(r) : "v"(lo), "v"(hi));
    return r;
}
// Bare v_exp_f32 (2^x): logits bounded |x| <~ 6, so the raw transcendental
// is safe (the ~6-op correctly-rounded __builtin_exp2f expansion is not needed).
__device__ __forceinline__ float fexp2(float x) {
    float r;
    asm("v_exp_f32 %0, %1" : "=v"(r) : "v"(x));
    return r;
}

// ---------------------------------------------------------------------------
// Kernel 0: merged conversions.
// ---------------------------------------------------------------------------
__global__ __launch_bounds__(256) void convert_all_kernel(
    const float* __restrict__ ts,
    const float* __restrict__ Wq,
    const float* __restrict__ topk,
    const float* __restrict__ Wk,
    const float* __restrict__ Wv,
    const float* __restrict__ Wo,
    const float* __restrict__ bo,
    uint16_t* __restrict__ tsbf,
    uint16_t* __restrict__ wqbf,
    uint16_t* __restrict__ topkbf,
    uint16_t* __restrict__ wkbf,
    uint16_t* __restrict__ wvbf,
    uint16_t* __restrict__ wobt)
{
    __shared__ float tile[32][65];
    int bid = blockIdx.x;
    int t = threadIdx.x;

    if (bid < 4096) {
        int i = bid * 256 + t;
        if (i < 524288) {
            tsbf[i] = f2bf(ts[i]);
        } else {
            int j = i - 524288;
            wqbf[j] = f2bf(Wq[(j >> 7) * 129 + (j & 127)]);
        }
    } else if (bid < 15488) {
        int r = bid - 4096;
        if (r < 3200) {
            if (t < 192) {
                float4 v = *(const float4*)(topk + (size_t)r * 768 + t * 4);
                uint2 u;
                u.x = pack2(v.x, v.y);
                u.y = pack2(v.z, v.w);
                *(uint2*)(topkbf + (size_t)r * 768 + t * 4) = u;
            }
        } else {
            int rr = r - 3200;
            const float* src;
            uint16_t* dst;
            if (rr < 4096) {
                src = Wk + (size_t)rr * 769;
                dst = wkbf + (size_t)rr * 768;
            } else {
                rr -= 4096;
                src = Wv + (size_t)rr * 769;
                dst = wvbf + (size_t)rr * 768;
            }
#pragma unroll
            for (int i = 0; i < 3; ++i)
                dst[t + 256 * i] = f2bf(src[t + 256 * i]);
        }
    } else {
        int b2 = bid - 15488;
        int kt = b2 / 12;
        int nb = b2 % 12;
        {
            int rr = t >> 3;
            int c0 = (t & 7) * 8;
            int kg = kt * 32 + rr;
            const float* src = (kg < 4096 ? Wo + (size_t)kg * DLLM
                                          : bo + (size_t)(kg - 4096) * DLLM)
                               + nb * 64 + c0;
            float4 v0 = *(const float4*)src;
            float4 v1 = *(const float4*)(src + 4);
            tile[rr][c0 + 0] = v0.x; tile[rr][c0 + 1] = v0.y;
            tile[rr][c0 + 2] = v0.z; tile[rr][c0 + 3] = v0.w;
            tile[rr][c0 + 4] = v1.x; tile[rr][c0 + 5] = v1.y;
            tile[rr][c0 + 6] = v1.z; tile[rr][c0 + 7] = v1.w;
        }
        __syncthreads();
        {
            int n  = t >> 2;
            int k0 = (t & 3) * 8;
            uint4 u;
            u.x = pack2(tile[k0 + 0][n], tile[k0 + 1][n]);
            u.y = pack2(tile[k0 + 2][n], tile[k0 + 3][n]);
            u.z = pack2(tile[k0 + 4][n], tile[k0 + 5][n]);
            u.w = pack2(tile[k0 + 6][n], tile[k0 + 7][n]);
            *(uint4*)&wobt[((size_t)(nb * 64 + n)) * KP + kt * 32 + k0] = u;
        }
    }
}

// ---------------------------------------------------------------------------
// Kernel 1+2 merged: K/V projection (blocks 0..255) + Q projection
// (blocks 256..1279). Unchanged from round 16.
// ---------------------------------------------------------------------------
__global__ __launch_bounds__(256) void proj_merged_kernel(
    const uint16_t* __restrict__ topkbf,  // [3200][768]
    const uint16_t* __restrict__ wkbf,    // [32*128][768]
    const uint16_t* __restrict__ wvbf,    // [32*128][768]
    const float* __restrict__ Wk,         // bias col
    const float* __restrict__ Wv,         // bias col
    uint16_t* __restrict__ kbuf,          // [32][112][128]
    uint16_t* __restrict__ vbufT,         // [32][128][128]
    const uint16_t* __restrict__ tsbf,    // [4096][128]
    const uint16_t* __restrict__ wqbf,    // [32][128][128]
    const float* __restrict__ Wq,         // bias col
    uint16_t* __restrict__ qbuf)
{
    __shared__ short As[2][4096];
    __shared__ short Bs[2][4096];

    int tid  = threadIdx.x;
    int lane = tid & 63;
    int w    = tid >> 6;
    int wr   = w >> 1;
    int wc   = w & 1;

    if (blockIdx.x < 256) {
        int bid = blockIdx.x;
        int nb = bid & 1;
        int mb = (bid >> 1) & 1;
        int c  = (bid >> 2) & 31;
        int which = bid >> 7;     // 0=K, 1=V

        int r16  = lane & 15;
        int kp   = lane >> 4;

        int arow = mb * 64 + w * 16 + r16;
        int brow = nb * 64 + w * 16 + r16;
        const uint16_t* aptr;
        const uint16_t* bptr;
        if (which == 0) {
            aptr = topkbf + ((size_t)(c * 100 + arow)) * 768 + kp * 8;
            bptr = wkbf   + ((size_t)(c * 128 + brow)) * 768 + kp * 8;
        } else {
            aptr = wvbf   + ((size_t)(c * 128 + arow)) * 768 + kp * 8;
            bptr = topkbf + ((size_t)(c * 100 + brow)) * 768 + kp * 8;
        }

        short* adst[2] = { &As[0][w * 512], &As[1][w * 512] };
        short* bdst[2] = { &Bs[0][w * 512], &Bs[1][w * 512] };

        f32x4 acc[2][2] = {};

        gload_lds16(aptr, adst[0]);
        gload_lds16(bptr, bdst[0]);
        __syncthreads();

        int cur = 0;
        for (int kt = 0; kt < 24; ++kt) {
            if (kt < 23) {
                gload_lds16(aptr + (kt + 1) * 32, adst[cur ^ 1]);
                gload_lds16(bptr + (kt + 1) * 32, bdst[cur ^ 1]);
            }
            const short* Ab = As[cur];
            const short* Bb = Bs[cur];
            bf16x8 a0 = *(const bf16x8*)(Ab + (wr * 2 + 0) * 512 + lane * 8);
            bf16x8 a1 = *(const bf16x8*)(Ab + (wr * 2 + 1) * 512 + lane * 8);
            bf16x8 b0 = *(const bf16x8*)(Bb + (wc * 2 + 0) * 512 + lane * 8);
            bf16x8 b1 = *(const bf16x8*)(Bb + (wc * 2 + 1) * 512 + lane * 8);
            acc[0][0] = __builtin_amdgcn_mfma_f32_16x16x32_bf16(a0, b0, acc[0][0], 0, 0, 0);
            acc[0][1] = __builtin_amdgcn_mfma_f32_16x16x32_bf16(a0, b1, acc[0][1], 0, 0, 0);
            acc[1][0] = __builtin_amdgcn_mfma_f32_16x16x32_bf16(a1, b0, acc[1][0], 0, 0, 0);
            acc[1][1] = __builtin_amdgcn_mfma_f32_16x16x32_bf16(a1, b1, acc[1][1], 0, 0, 0);
            __syncthreads();
            cur ^= 1;
        }

        int mbase = mb * 64 + wr * 32 + (lane >> 4) * 4;
        int nbase = nb * 64 + wc * 32 + (lane & 15);

        if (which == 0) {
            float bias0 = Wk[((size_t)c * 128 + nbase)      * 769 + 768];
            float bias1 = Wk[((size_t)c * 128 + nbase + 16) * 769 + 768];
#pragma unroll
            for (int fm = 0; fm < 2; ++fm)
#pragma unroll
                for (int r = 0; r < 4; ++r) {
                    int mrow = mbase + fm * 16 + r;
                    if (mrow < 112) {
                        kbuf[((size_t)c * 112 + mrow) * 128 + nbase]      = f2bf(acc[fm][0][r] + bias0);
                        kbuf[((size_t)c * 112 + mrow) * 128 + nbase + 16] = f2bf(acc[fm][1][r] + bias1);
                    }
                }
        } else {
#pragma unroll
            for (int fm = 0; fm < 2; ++fm)
#pragma unroll
                for (int r = 0; r < 4; ++r) {
                    int grow = mbase + fm * 16 + r;
                    float bias = Wv[((size_t)c * 128 + grow) * 769 + 768];
#pragma unroll
                    for (int fn = 0; fn < 2; ++fn) {
                        int ncol = nbase + fn * 16;
                        uint16_t val = (ncol < NK) ? f2bf(acc[fm][fn][r] + bias) : (uint16_t)0;
                        vbufT[((size_t)c * 128 + grow) * 128 + ncol] = val;
                    }
                }
        }
    } else {
        int bid = blockIdx.x - 256;
        int mb = bid & 31;
        int c  = bid >> 5;

        int sg  = tid >> 6;
        int skp = (tid >> 4) & 3;
        int sr  = tid & 15;
        const uint16_t* aptr = tsbf + ((size_t)(mb * 128 + sg * 16 + sr)) * 128 + skp * 8;
        const uint16_t* bptr = wqbf + ((size_t)(c * 128 + sg * 16 + sr)) * 128 + skp * 8;

        short* adst[2] = { &As[0][w * 512], &As[1][w * 512] };
        short* bdst[2] = { &Bs[0][w * 512], &Bs[1][w * 512] };

        f32x4 acc[4][4] = {};

        gload_lds16(aptr, adst[0]);
        gload_lds16(aptr + (size_t)64 * 128, adst[0] + 2048);
        gload_lds16(bptr, bdst[0]);
        gload_lds16(bptr + (size_t)64 * 128, bdst[0] + 2048);
        __syncthreads();

        int cur = 0;
        for (int kt = 0; kt < 4; ++kt) {
            if (kt < 3) {
                const uint16_t* ap = aptr + (kt + 1) * 32;
                const uint16_t* bp = bptr + (kt + 1) * 32;
                gload_lds16(ap, adst[cur ^ 1]);
                gload_lds16(ap + (size_t)64 * 128, adst[cur ^ 1] + 2048);
                gload_lds16(bp, bdst[cur ^ 1]);
                gload_lds16(bp + (size_t)64 * 128, bdst[cur ^ 1] + 2048);
            }
            const short* Ab = As[cur];
            const short* Bb = Bs[cur];
            bf16x8 av[4], bv[4];
#pragma unroll
            for (int m = 0; m < 4; ++m)
                av[m] = *(const bf16x8*)(Ab + (wr * 4 + m) * 512 + lane * 8);
#pragma unroll
            for (int n = 0; n < 4; ++n)
                bv[n] = *(const bf16x8*)(Bb + (wc * 4 + n) * 512 + lane * 8);
#pragma unroll
            for (int m = 0; m < 4; ++m)
#pragma unroll
                for (int n = 0; n < 4; ++n)
                    acc[m][n] = __builtin_amdgcn_mfma_f32_16x16x32_bf16(av[m], bv[n], acc[m][n], 0, 0, 0);
            __syncthreads();
            cur ^= 1;
        }

        int mbase = mb * 128 + wr * 64 + (lane >> 4) * 4;
        int nfix  = wc * 64 + (lane & 15);
#pragma unroll
        for (int n = 0; n < 4; ++n) {
            int ncol = nfix + n * 16;
            float bias = Wq[((size_t)c * 128 + ncol) * 129 + 128];
#pragma unroll
            for (int m = 0; m < 4; ++m)
#pragma unroll
                for (int r = 0; r < 4; ++r)
                    qbuf[((size_t)c * 4096 + mbase + m * 16 + r) * 128 + ncol] =
                        f2bf((acc[m][n][r] + bias) * QSCL);
        }
    }
}

// ---------------------------------------------------------------------------
// Kernel 3: MFMA attention (round-12 structure) + T5 s_setprio around the
// MFMA clusters (m191: +4-7% on attn with independent co-resident blocks).
// LDS = 64 KiB exactly.
// ---------------------------------------------------------------------------
__global__ __launch_bounds__(256) void attn_mfma_kernel(
    const uint16_t* __restrict__ qbuf,
    const uint16_t* __restrict__ kbuf,
    const uint16_t* __restrict__ vbufT,
    const float* __restrict__ probs,
    uint16_t* __restrict__ wout)
{
    __shared__ short Pl[4][64][128];   // 65536 B == 64 KiB exactly

    int bid = blockIdx.x;
    int c = bid >> 6;
    int b = bid & 63;
    int tid = threadIdx.x;
    int lane = tid & 63;
    int w = tid >> 6;
    int g = lane >> 4;        // 0..3
    int l15 = lane & 15;
    int swz = l15 << 4;       // 16B-block XOR swizzle key

    float pr_tok = probs[((size_t)b * 64 + lane) * NC + c];

    uint8_t* Pb = (uint8_t*)&Pl[w][0][0];
    bf16x8 zf = {};

    for (int hh = 0; hh < 2; ++hh) {
        int h = w * 2 + hh;

        // Q fragments (B-operand): groups 0,1 real (d 0..15), groups 2,3 zero
        bf16x8 qb[4];
#pragma unroll
        for (int nt = 0; nt < 4; ++nt) {
            if (g < 2)
                qb[nt] = *(const bf16x8*)&qbuf[((size_t)c * 4096 + b * 64 + nt * 16 + l15) * 128 + h * 16 + g * 8];
            else
                qb[nt] = zf;
        }

        float psum[4] = {0.f, 0.f, 0.f, 0.f};
#pragma unroll
        for (int mt = 0; mt < 7; ++mt) {
            bf16x8 ka;
            if (g < 2)
                ka = *(const bf16x8*)&kbuf[((size_t)c * 112 + mt * 16 + l15) * 128 + h * 16 + g * 8];
            else
                ka = zf;
            f32x4 s[4];
            __builtin_amdgcn_s_setprio(1);
#pragma unroll
            for (int nt = 0; nt < 4; ++nt)
                s[nt] = __builtin_amdgcn_mfma_f32_16x16x32_bf16(ka, qb[nt], (f32x4){0.f,0.f,0.f,0.f}, 0, 0, 0);
            __builtin_amdgcn_s_setprio(0);
            // rows k = mt*16 + 4g + r ; valid iff k < 100
            bool valid = (mt < 6) || (g == 0);
#pragma unroll
            for (int nt = 0; nt < 4; ++nt) {
                float p0 = valid ? fexp2(s[nt][0]) : 0.f;
                float p1 = valid ? fexp2(s[nt][1]) : 0.f;
                float p2 = valid ? fexp2(s[nt][2]) : 0.f;
                float p3 = valid ? fexp2(s[nt][3]) : 0.f;
                psum[nt] += (p0 + p1) + (p2 + p3);
                union { uint32_t u[2]; bf16x4 v; } pk;
                pk.u[0] = cvtpk_bf16(p0, p1);
                pk.u[1] = cvtpk_bf16(p2, p3);
                int l = nt * 16 + l15;
                *(bf16x4*)(Pb + l * 256 + ((mt * 32 + g * 8) ^ swz)) = pk.v;
            }
        }
        // zero pad P cols 112..127
        {
            bf16x4 z4 = {};
#pragma unroll
            for (int nt = 0; nt < 4; ++nt) {
                int l = nt * 16 + l15;
                *(bf16x4*)(Pb + l * 256 + ((224 + g * 8) ^ swz)) = z4;
            }
        }
        // fence: all P ds_writes visible before PV ds_reads
        __syncthreads();

        // full softmax denominators -> registers (every lane gets all copies)
        float rsum[4];
#pragma unroll
        for (int nt = 0; nt < 4; ++nt) {
            float t = psum[nt];
            t += __shfl_xor(t, 16);
            t += __shfl_xor(t, 32);
            rsum[nt] = __builtin_amdgcn_rcpf(t);   // 1/sum for token nt*16+l15
        }

        // PV: oacc[l-tile] over 4 k-chunks of 32
        f32x4 oacc[4] = {};
        __builtin_amdgcn_s_setprio(1);
#pragma unroll
        for (int ch = 0; ch < 4; ++ch) {
            bf16x8 vb = *(const bf16x8*)&vbufT[((size_t)c * 128 + h * 16 + l15) * 128 + ch * 32 + g * 8];
#pragma unroll
            for (int mt = 0; mt < 4; ++mt) {
                int l = mt * 16 + l15;
                bf16x8 pa = *(const bf16x8*)(Pb + l * 256 + ((ch * 64 + g * 16) ^ swz));
                oacc[mt] = __builtin_amdgcn_mfma_f32_16x16x32_bf16(pa, vb, oacc[mt], 0, 0, 0);
            }
        }
        __builtin_amdgcn_s_setprio(0);
        // epilogue: out[l][d], col d = lane&15, row l = mt*16 + 4g + r
#pragma unroll
        for (int mt = 0; mt < 4; ++mt) {
#pragma unroll
            for (int r = 0; r < 4; ++r) {
                int l = mt * 16 + g * 4 + r;
                float sc = __shfl(pr_tok, l) * __shfl(rsum[mt], g * 4 + r);
                wout[((size_t)b * 64 + l) * KP + c * 128 + h * 16 + l15] =
                    f2bf(oacc[mt][r] * sc);
            }
        }
        // fence: PV ds_reads done before next head's P ds_writes (WAR)
        __syncthreads();
    }
    // probs tail column
    if (tid < 64)
        wout[((size_t)b * 64 + tid) * KP + 4096 + c] = f2bf(pr_tok);
}

// ---------------------------------------------------------------------------
// Kernel 4a (fallback when no workspace slack): [Wo;bo] -> WoBT, after attn.
// ---------------------------------------------------------------------------
__global__ __launch_bounds__(256) void convert_wo_kernel(
    const float* __restrict__ Wo,
    const float* __restrict__ bo,
    uint16_t* __restrict__ wobt)
{
    __shared__ float tile[32][65];
    int bid = blockIdx.x;
    int kt = bid / 12;
    int nb = bid % 12;
    int t = threadIdx.x;
    {
        int rr = t >> 3;
        int c0 = (t & 7) * 8;
        int kg = kt * 32 + rr;
        const float* src = (kg < 4096 ? Wo + (size_t)kg * DLLM
                                      : bo + (size_t)(kg - 4096) * DLLM)
                           + nb * 64 + c0;
        float4 v0 = *(const float4*)src;
        float4 v1 = *(const float4*)(src + 4);
        tile[rr][c0 + 0] = v0.x; tile[rr][c0 + 1] = v0.y;
        tile[rr][c0 + 2] = v0.z; tile[rr][c0 + 3] = v0.w;
        tile[rr][c0 + 4] = v1.x; tile[rr][c0 + 5] = v1.y;
        tile[rr][c0 + 6] = v1.z; tile[rr][c0 + 7] = v1.w;
    }
    __syncthreads();
    {
        int n  = t >> 2;
        int k0 = (t & 3) * 8;
        uint4 u;
        u.x = pack2(tile[k0 + 0][n], tile[k0 + 1][n]);
        u.y = pack2(tile[k0 + 2][n], tile[k0 + 3][n]);
        u.z = pack2(tile[k0 + 4][n], tile[k0 + 5][n]);
        u.w = pack2(tile[k0 + 6][n], tile[k0 + 7][n]);
        *(uint4*)&wobt[((size_t)(nb * 64 + n)) * KP + kt * 32 + k0] = u;
    }
}

// ---------------------------------------------------------------------------
// Kernel 4b: split-K MFMA GEMM, 128x128 tile (round-12 proven body, exact
// restore). Six structural variants (r13 BK=64, r14 64sq x1536, r15 counted
// vmcnt, r17 128x192 x256) all landed at 56-92 us; 56 us is this structure's
// floor at N=768 -- co-resident-block overlap (2 blocks/CU on loaded CUs) is
// what r12 gets right.
// ---------------------------------------------------------------------------
__global__ __launch_bounds__(256) void fgemm_splitk_kernel(
    const uint16_t* __restrict__ wout,   // A  [4096][4128] bf16
    const uint16_t* __restrict__ wobt,   // B^T [768][4128] bf16
    float* __restrict__ part)            // [2][4096][768] fp32
{
    __shared__ short As[2][4096];
    __shared__ short Bs[2][4096];

    int bid = blockIdx.x;
    int swz = (bid & 7) * 48 + (bid >> 3);   // bijective on [0,384)
    int h  = swz / 192;                       // k-half
    int rr = swz - h * 192;
    int mb = rr / 6;                          // 0..31
    int nb = rr - mb * 6;                     // 0..5

    int tid  = threadIdx.x;
    int lane = tid & 63;
    int w    = tid >> 6;
    int wr   = w >> 1;
    int wc   = w & 1;

    int sg = tid >> 6;
    int skp = (tid >> 4) & 3;
    int sr = tid & 15;
    const uint16_t* aptr = wout + ((size_t)(mb * 128 + sg * 16 + sr)) * KP + h * 2048 + skp * 8;
    const uint16_t* bptr = wobt + ((size_t)(nb * 128 + sg * 16 + sr)) * KP + h * 2048 + skp * 8;

    short* adst[2] = { &As[0][w * 512], &As[1][w * 512] };
    short* bdst[2] = { &Bs[0][w * 512], &Bs[1][w * 512] };

    int nkt = h ? 65 : 64;

    f32x4 acc[4][4] = {};

    gload_lds16(aptr, adst[0]);
    gload_lds16(aptr + (size_t)64 * KP, adst[0] + 2048);
    gload_lds16(bptr, bdst[0]);
    gload_lds16(bptr + (size_t)64 * KP, bdst[0] + 2048);
    __syncthreads();

    int cur = 0;
    for (int kt = 0; kt < nkt; ++kt) {
        if (kt + 1 < nkt) {
            const uint16_t* ap = aptr + (size_t)(kt + 1) * 32;
            const uint16_t* bp = bptr + (size_t)(kt + 1) * 32;
            gload_lds16(ap, adst[cur ^ 1]);
            gload_lds16(ap + (size_t)64 * KP, adst[cur ^ 1] + 2048);
            gload_lds16(bp, bdst[cur ^ 1]);
            gload_lds16(bp + (size_t)64 * KP, bdst[cur ^ 1] + 2048);
        }
        const short* Ab = As[cur];
        const short* Bb = Bs[cur];
        bf16x8 av[4], bv[4];
#pragma unroll
        for (int m = 0; m < 4; ++m)
            av[m] = *(const bf16x8*)(Ab + (wr * 4 + m) * 512 + lane * 8);
#pragma unroll
        for (int n = 0; n < 4; ++n)
            bv[n] = *(const bf16x8*)(Bb + (wc * 4 + n) * 512 + lane * 8);
#pragma unroll
        for (int m = 0; m < 4; ++m)
#pragma unroll
            for (int n = 0; n < 4; ++n)
                acc[m][n] = __builtin_amdgcn_mfma_f32_16x16x32_bf16(av[m], bv[n], acc[m][n], 0, 0, 0);
        __syncthreads();
        cur ^= 1;
    }

    float* P = part + (size_t)h * (4096 * 768);
    int mbase = mb * 128 + wr * 64 + (lane >> 4) * 4;
    int nbase = nb * 128 + wc * 64 + (lane & 15);
#pragma unroll
    for (int m = 0; m < 4; ++m)
#pragma unroll
        for (int n = 0; n < 4; ++n)
#pragma unroll
            for (int r = 0; r < 4; ++r)
                P[(size_t)(mbase + m * 16 + r) * DLLM + nbase + n * 16] =
                    acc[m][n][r];
}

// ---------------------------------------------------------------------------
// Kernel 4c: reduce the two K-half partials into the fp32 output.
// ---------------------------------------------------------------------------
__global__ __launch_bounds__(256) void reduce_out_kernel(
    const float* __restrict__ part,
    float* __restrict__ out)
{
    int i = (blockIdx.x * 256 + threadIdx.x) * 4;
    float4 a = *(const float4*)(part + i);
    float4 b = *(const float4*)(part + 4096 * 768 + i);
    float4 s;
    s.x = a.x + b.x; s.y = a.y + b.y; s.z = a.z + b.z; s.w = a.w + b.w;
    *(float4*)(out + i) = s;
}

// ---------------------------------------------------------------------------
extern "C" void kernel_launch(void* const* d_in, const int* in_sizes, int n_in,
                              void* d_out, int out_size, void* d_ws, size_t ws_size,
                              hipStream_t stream) {
    const float* topk  = (const float*)d_in[0];  // (32,100,768)
    const float* ts    = (const float*)d_in[1];  // (64,64,128)
    const float* probs = (const float*)d_in[2];  // (64,64,32)
    const float* Wq    = (const float*)d_in[3];  // (32,128,129)
    const float* Wk    = (const float*)d_in[4];  // (32,128,769)
    const float* Wv    = (const float*)d_in[5];  // (32,128,769)
    const float* Wo    = (const float*)d_in[6];  // (32,128,768)
    const float* bo    = (const float*)d_in[7];  // (32,768)
    float* out = (float*)d_out;

    // workspace (uint16): kbuf | vbufT | qbuf | wout
    uint16_t* ws    = (uint16_t*)d_ws;
    uint16_t* kbuf  = ws;                          // 32*112*128  = 458752
    uint16_t* vbufT = ws + 458752;                 // 32*128*128  = 524288
    uint16_t* qbuf  = ws + 983040;                 // 32*4096*128 = 16777216
    uint16_t* wout  = ws + 983040 + 16777216;      // 4096*4128   = 16908288
    // overlays inside wout region (all dead before attn writes wout):
    uint16_t* tsbf   = wout;                       // 524288   (dead after proj)
    uint16_t* wqbf   = wout + 524288;              // 524288   (dead after proj)
    uint16_t* topkbf = wout + 1048576;             // 2457600  (dead after proj)
    uint16_t* wkbf   = wout + 1048576 + 2457600;   // 3145728  (dead after proj)
    uint16_t* wvbf   = wout + 1048576 + 2457600 + 3145728;  // 3145728, ends 9797632
    // part overlays qbuf region (dead after attn):
    float* part = (float*)(qbuf + 3170304);        // 2*4096*768 fp32 = 25.2 MB

    // wout ends at short-index 983040+16777216+16908288 = 34,668,544.
    const size_t BASE = 34668544;                  // first free short after wout
    bool slack = ws_size >= (BASE + 3170304) * sizeof(uint16_t);
    uint16_t* wobt = slack ? (ws + BASE) : qbuf;

    int nconv = slack ? 17036 : 15488;
    convert_all_kernel<<<nconv, 256, 0, stream>>>(ts, Wq, topk, Wk, Wv, Wo, bo,
                                                  tsbf, wqbf, topkbf, wkbf, wvbf, wobt);
    proj_merged_kernel<<<1280, 256, 0, stream>>>(topkbf, wkbf, wvbf, Wk, Wv,
                                                 kbuf, vbufT, tsbf, wqbf, Wq, qbuf);
    attn_mfma_kernel<<<2048, 256, 0, stream>>>(qbuf, kbuf, vbufT, probs, wout);
    if (!slack)
        convert_wo_kernel<<<1548, 256, 0, stream>>>(Wo, bo, wobt);
    fgemm_splitk_kernel<<<384, 256, 0, stream>>>(wout, wobt, part);
    reduce_out_kernel<<<3072, 256, 0, stream>>>(part, out);
}

// Round 19
// 150.463 us; speedup vs baseline: 1.2556x; 1.0158x over previous
//
#include <hip/hip_runtime.h>
#include <stdint.h>

// Dims
#define NB 64
#define NL 64
#define NC 32
#define NK 100
#define NH 8
#define DKEY 16
#define DM 128
#define NG 128       // H*DKEY
#define DLLM 768
#define KP 4128      // 4096 + 32 (probs tail) : wout row stride
#define TEMP 0.25f   // 1/sqrt(16)
#define QSCL 0.3606737602222409f   // TEMP * log2(e): folded into Q so P = exp2(S)

typedef __attribute__((ext_vector_type(8))) short bf16x8;
typedef __attribute__((ext_vector_type(4))) short bf16x4;
typedef __attribute__((ext_vector_type(4))) float f32x4;

typedef uint32_t __attribute__((address_space(1))) gu32;
typedef uint32_t __attribute__((address_space(3))) lu32;

__device__ __forceinline__ void gload_lds16(const void* g, void* l) {
    __builtin_amdgcn_global_load_lds((const gu32*)g, (lu32*)l, 16, 0, 0);
}

// ---------- bf16 helpers ----------
__device__ __forceinline__ uint16_t f2bf(float f) {
    union { float f; uint32_t i; } x; x.f = f;
    uint32_t r = x.i + 0x7FFFu + ((x.i >> 16) & 1u);
    return (uint16_t)(r >> 16);
}
__device__ __forceinline__ uint32_t pack2(float lo, float hi) {
    return (uint32_t)f2bf(lo) | ((uint32_t)f2bf(hi) << 16);
}
__device__ __forceinline__ uint32_t cvtpk_bf16(float lo, float hi) {
    uint32_t r;
    asm("v_cvt_pk_bf16_f32 %0, %1, %2" : "=v"(r) : "v"(lo), "v"(hi));
    return r;
}
// Bare v_exp_f32 (2^x): logits bounded |x| <~ 6, so the raw transcendental
// is safe (the ~6-op correctly-rounded __builtin_exp2f expansion is not needed).
__device__ __forceinline__ float fexp2(float x) {
    float r;
    asm("v_exp_f32 %0, %1" : "=v"(r) : "v"(x));
    return r;
}

// ---------------------------------------------------------------------------
// Kernel 0: merged conversions.
// ---------------------------------------------------------------------------
__global__ __launch_bounds__(256) void convert_all_kernel(
    const float* __restrict__ ts,
    const float* __restrict__ Wq,
    const float* __restrict__ topk,
    const float* __restrict__ Wk,
    const float* __restrict__ Wv,
    const float* __restrict__ Wo,
    const float* __restrict__ bo,
    uint16_t* __restrict__ tsbf,
    uint16_t* __restrict__ wqbf,
    uint16_t* __restrict__ topkbf,
    uint16_t* __restrict__ wkbf,
    uint16_t* __restrict__ wvbf,
    uint16_t* __restrict__ wobt)
{
    __shared__ float tile[32][65];
    int bid = blockIdx.x;
    int t = threadIdx.x;

    if (bid < 4096) {
        int i = bid * 256 + t;
        if (i < 524288) {
            tsbf[i] = f2bf(ts[i]);
        } else {
            int j = i - 524288;
            wqbf[j] = f2bf(Wq[(j >> 7) * 129 + (j & 127)]);
        }
    } else if (bid < 15488) {
        int r = bid - 4096;
        if (r < 3200) {
            if (t < 192) {
                float4 v = *(const float4*)(topk + (size_t)r * 768 + t * 4);
                uint2 u;
                u.x = pack2(v.x, v.y);
                u.y = pack2(v.z, v.w);
                *(uint2*)(topkbf + (size_t)r * 768 + t * 4) = u;
            }
        } else {
            int rr = r - 3200;
            const float* src;
            uint16_t* dst;
            if (rr < 4096) {
                src = Wk + (size_t)rr * 769;
                dst = wkbf + (size_t)rr * 768;
            } else {
                rr -= 4096;
                src = Wv + (size_t)rr * 769;
                dst = wvbf + (size_t)rr * 768;
            }
#pragma unroll
            for (int i = 0; i < 3; ++i)
                dst[t + 256 * i] = f2bf(src[t + 256 * i]);
        }
    } else {
        int b2 = bid - 15488;
        int kt = b2 / 12;
        int nb = b2 % 12;
        {
            int rr = t >> 3;
            int c0 = (t & 7) * 8;
            int kg = kt * 32 + rr;
            const float* src = (kg < 4096 ? Wo + (size_t)kg * DLLM
                                          : bo + (size_t)(kg - 4096) * DLLM)
                               + nb * 64 + c0;
            float4 v0 = *(const float4*)src;
            float4 v1 = *(const float4*)(src + 4);
            tile[rr][c0 + 0] = v0.x; tile[rr][c0 + 1] = v0.y;
            tile[rr][c0 + 2] = v0.z; tile[rr][c0 + 3] = v0.w;
            tile[rr][c0 + 4] = v1.x; tile[rr][c0 + 5] = v1.y;
            tile[rr][c0 + 6] = v1.z; tile[rr][c0 + 7] = v1.w;
        }
        __syncthreads();
        {
            int n  = t >> 2;
            int k0 = (t & 3) * 8;
            uint4 u;
            u.x = pack2(tile[k0 + 0][n], tile[k0 + 1][n]);
            u.y = pack2(tile[k0 + 2][n], tile[k0 + 3][n]);
            u.z = pack2(tile[k0 + 4][n], tile[k0 + 5][n]);
            u.w = pack2(tile[k0 + 6][n], tile[k0 + 7][n]);
            *(uint4*)&wobt[((size_t)(nb * 64 + n)) * KP + kt * 32 + k0] = u;
        }
    }
}

// ---------------------------------------------------------------------------
// Kernel 1+2 merged: K/V projection (blocks 0..255) + Q projection
// (blocks 256..1279).
// ---------------------------------------------------------------------------
__global__ __launch_bounds__(256) void proj_merged_kernel(
    const uint16_t* __restrict__ topkbf,  // [3200][768]
    const uint16_t* __restrict__ wkbf,    // [32*128][768]
    const uint16_t* __restrict__ wvbf,    // [32*128][768]
    const float* __restrict__ Wk,         // bias col
    const float* __restrict__ Wv,         // bias col
    uint16_t* __restrict__ kbuf,          // [32][112][128]
    uint16_t* __restrict__ vbufT,         // [32][128][128]
    const uint16_t* __restrict__ tsbf,    // [4096][128]
    const uint16_t* __restrict__ wqbf,    // [32][128][128]
    const float* __restrict__ Wq,         // bias col
    uint16_t* __restrict__ qbuf)
{
    __shared__ short As[2][4096];
    __shared__ short Bs[2][4096];

    int tid  = threadIdx.x;
    int lane = tid & 63;
    int w    = tid >> 6;
    int wr   = w >> 1;
    int wc   = w & 1;

    if (blockIdx.x < 256) {
        int bid = blockIdx.x;
        int nb = bid & 1;
        int mb = (bid >> 1) & 1;
        int c  = (bid >> 2) & 31;
        int which = bid >> 7;     // 0=K, 1=V

        int r16  = lane & 15;
        int kp   = lane >> 4;

        int arow = mb * 64 + w * 16 + r16;
        int brow = nb * 64 + w * 16 + r16;
        const uint16_t* aptr;
        const uint16_t* bptr;
        if (which == 0) {
            aptr = topkbf + ((size_t)(c * 100 + arow)) * 768 + kp * 8;
            bptr = wkbf   + ((size_t)(c * 128 + brow)) * 768 + kp * 8;
        } else {
            aptr = wvbf   + ((size_t)(c * 128 + arow)) * 768 + kp * 8;
            bptr = topkbf + ((size_t)(c * 100 + brow)) * 768 + kp * 8;
        }

        short* adst[2] = { &As[0][w * 512], &As[1][w * 512] };
        short* bdst[2] = { &Bs[0][w * 512], &Bs[1][w * 512] };

        f32x4 acc[2][2] = {};

        gload_lds16(aptr, adst[0]);
        gload_lds16(bptr, bdst[0]);
        __syncthreads();

        int cur = 0;
        for (int kt = 0; kt < 24; ++kt) {
            if (kt < 23) {
                gload_lds16(aptr + (kt + 1) * 32, adst[cur ^ 1]);
                gload_lds16(bptr + (kt + 1) * 32, bdst[cur ^ 1]);
            }
            const short* Ab = As[cur];
            const short* Bb = Bs[cur];
            bf16x8 a0 = *(const bf16x8*)(Ab + (wr * 2 + 0) * 512 + lane * 8);
            bf16x8 a1 = *(const bf16x8*)(Ab + (wr * 2 + 1) * 512 + lane * 8);
            bf16x8 b0 = *(const bf16x8*)(Bb + (wc * 2 + 0) * 512 + lane * 8);
            bf16x8 b1 = *(const bf16x8*)(Bb + (wc * 2 + 1) * 512 + lane * 8);
            acc[0][0] = __builtin_amdgcn_mfma_f32_16x16x32_bf16(a0, b0, acc[0][0], 0, 0, 0);
            acc[0][1] = __builtin_amdgcn_mfma_f32_16x16x32_bf16(a0, b1, acc[0][1], 0, 0, 0);
            acc[1][0] = __builtin_amdgcn_mfma_f32_16x16x32_bf16(a1, b0, acc[1][0], 0, 0, 0);
            acc[1][1] = __builtin_amdgcn_mfma_f32_16x16x32_bf16(a1, b1, acc[1][1], 0, 0, 0);
            __syncthreads();
            cur ^= 1;
        }

        int mbase = mb * 64 + wr * 32 + (lane >> 4) * 4;
        int nbase = nb * 64 + wc * 32 + (lane & 15);

        if (which == 0) {
            float bias0 = Wk[((size_t)c * 128 + nbase)      * 769 + 768];
            float bias1 = Wk[((size_t)c * 128 + nbase + 16) * 769 + 768];
#pragma unroll
            for (int fm = 0; fm < 2; ++fm)
#pragma unroll
                for (int r = 0; r < 4; ++r) {
                    int mrow = mbase + fm * 16 + r;
                    if (mrow < 112) {
                        kbuf[((size_t)c * 112 + mrow) * 128 + nbase]      = f2bf(acc[fm][0][r] + bias0);
                        kbuf[((size_t)c * 112 + mrow) * 128 + nbase + 16] = f2bf(acc[fm][1][r] + bias1);
                    }
                }
        } else {
#pragma unroll
            for (int fm = 0; fm < 2; ++fm)
#pragma unroll
                for (int r = 0; r < 4; ++r) {
                    int grow = mbase + fm * 16 + r;
                    float bias = Wv[((size_t)c * 128 + grow) * 769 + 768];
#pragma unroll
                    for (int fn = 0; fn < 2; ++fn) {
                        int ncol = nbase + fn * 16;
                        uint16_t val = (ncol < NK) ? f2bf(acc[fm][fn][r] + bias) : (uint16_t)0;
                        vbufT[((size_t)c * 128 + grow) * 128 + ncol] = val;
                    }
                }
        }
    } else {
        int bid = blockIdx.x - 256;
        int mb = bid & 31;
        int c  = bid >> 5;

        int sg  = tid >> 6;
        int skp = (tid >> 4) & 3;
        int sr  = tid & 15;
        const uint16_t* aptr = tsbf + ((size_t)(mb * 128 + sg * 16 + sr)) * 128 + skp * 8;
        const uint16_t* bptr = wqbf + ((size_t)(c * 128 + sg * 16 + sr)) * 128 + skp * 8;

        short* adst[2] = { &As[0][w * 512], &As[1][w * 512] };
        short* bdst[2] = { &Bs[0][w * 512], &Bs[1][w * 512] };

        f32x4 acc[4][4] = {};

        gload_lds16(aptr, adst[0]);
        gload_lds16(aptr + (size_t)64 * 128, adst[0] + 2048);
        gload_lds16(bptr, bdst[0]);
        gload_lds16(bptr + (size_t)64 * 128, bdst[0] + 2048);
        __syncthreads();

        int cur = 0;
        for (int kt = 0; kt < 4; ++kt) {
            if (kt < 3) {
                const uint16_t* ap = aptr + (kt + 1) * 32;
                const uint16_t* bp = bptr + (kt + 1) * 32;
                gload_lds16(ap, adst[cur ^ 1]);
                gload_lds16(ap + (size_t)64 * 128, adst[cur ^ 1] + 2048);
                gload_lds16(bp, bdst[cur ^ 1]);
                gload_lds16(bp + (size_t)64 * 128, bdst[cur ^ 1] + 2048);
            }
            const short* Ab = As[cur];
            const short* Bb = Bs[cur];
            bf16x8 av[4], bv[4];
#pragma unroll
            for (int m = 0; m < 4; ++m)
                av[m] = *(const bf16x8*)(Ab + (wr * 4 + m) * 512 + lane * 8);
#pragma unroll
            for (int n = 0; n < 4; ++n)
                bv[n] = *(const bf16x8*)(Bb + (wc * 4 + n) * 512 + lane * 8);
#pragma unroll
            for (int m = 0; m < 4; ++m)
#pragma unroll
                for (int n = 0; n < 4; ++n)
                    acc[m][n] = __builtin_amdgcn_mfma_f32_16x16x32_bf16(av[m], bv[n], acc[m][n], 0, 0, 0);
            __syncthreads();
            cur ^= 1;
        }

        int mbase = mb * 128 + wr * 64 + (lane >> 4) * 4;
        int nfix  = wc * 64 + (lane & 15);
#pragma unroll
        for (int n = 0; n < 4; ++n) {
            int ncol = nfix + n * 16;
            float bias = Wq[((size_t)c * 128 + ncol) * 129 + 128];
#pragma unroll
            for (int m = 0; m < 4; ++m)
#pragma unroll
                for (int r = 0; r < 4; ++r)
                    qbuf[((size_t)c * 4096 + mbase + m * 16 + r) * 128 + ncol] =
                        f2bf((acc[m][n][r] + bias) * QSCL);
        }
    }
}

// ---------------------------------------------------------------------------
// Kernel 3: MFMA attention (round-12 structure: round-7 proven body +
// QSCL fold + bare v_exp_f32; setprio removed -- r18 A/B showed null/neg).
// LDS = 64 KiB exactly.
// ---------------------------------------------------------------------------
__global__ __launch_bounds__(256) void attn_mfma_kernel(
    const uint16_t* __restrict__ qbuf,
    const uint16_t* __restrict__ kbuf,
    const uint16_t* __restrict__ vbufT,
    const float* __restrict__ probs,
    uint16_t* __restrict__ wout)
{
    __shared__ short Pl[4][64][128];   // 65536 B == 64 KiB exactly

    int bid = blockIdx.x;
    int c = bid >> 6;
    int b = bid & 63;
    int tid = threadIdx.x;
    int lane = tid & 63;
    int w = tid >> 6;
    int g = lane >> 4;        // 0..3
    int l15 = lane & 15;
    int swz = l15 << 4;       // 16B-block XOR swizzle key

    float pr_tok = probs[((size_t)b * 64 + lane) * NC + c];

    uint8_t* Pb = (uint8_t*)&Pl[w][0][0];
    bf16x8 zf = {};

    for (int hh = 0; hh < 2; ++hh) {
        int h = w * 2 + hh;

        // Q fragments (B-operand): groups 0,1 real (d 0..15), groups 2,3 zero
        bf16x8 qb[4];
#pragma unroll
        for (int nt = 0; nt < 4; ++nt) {
            if (g < 2)
                qb[nt] = *(const bf16x8*)&qbuf[((size_t)c * 4096 + b * 64 + nt * 16 + l15) * 128 + h * 16 + g * 8];
            else
                qb[nt] = zf;
        }

        float psum[4] = {0.f, 0.f, 0.f, 0.f};
#pragma unroll
        for (int mt = 0; mt < 7; ++mt) {
            bf16x8 ka;
            if (g < 2)
                ka = *(const bf16x8*)&kbuf[((size_t)c * 112 + mt * 16 + l15) * 128 + h * 16 + g * 8];
            else
                ka = zf;
            f32x4 s[4];
#pragma unroll
            for (int nt = 0; nt < 4; ++nt)
                s[nt] = __builtin_amdgcn_mfma_f32_16x16x32_bf16(ka, qb[nt], (f32x4){0.f,0.f,0.f,0.f}, 0, 0, 0);
            // rows k = mt*16 + 4g + r ; valid iff k < 100
            bool valid = (mt < 6) || (g == 0);
#pragma unroll
            for (int nt = 0; nt < 4; ++nt) {
                float p0 = valid ? fexp2(s[nt][0]) : 0.f;
                float p1 = valid ? fexp2(s[nt][1]) : 0.f;
                float p2 = valid ? fexp2(s[nt][2]) : 0.f;
                float p3 = valid ? fexp2(s[nt][3]) : 0.f;
                psum[nt] += (p0 + p1) + (p2 + p3);
                union { uint32_t u[2]; bf16x4 v; } pk;
                pk.u[0] = cvtpk_bf16(p0, p1);
                pk.u[1] = cvtpk_bf16(p2, p3);
                int l = nt * 16 + l15;
                *(bf16x4*)(Pb + l * 256 + ((mt * 32 + g * 8) ^ swz)) = pk.v;
            }
        }
        // zero pad P cols 112..127
        {
            bf16x4 z4 = {};
#pragma unroll
            for (int nt = 0; nt < 4; ++nt) {
                int l = nt * 16 + l15;
                *(bf16x4*)(Pb + l * 256 + ((224 + g * 8) ^ swz)) = z4;
            }
        }
        // fence: all P ds_writes visible before PV ds_reads
        __syncthreads();

        // full softmax denominators -> registers (every lane gets all copies)
        float rsum[4];
#pragma unroll
        for (int nt = 0; nt < 4; ++nt) {
            float t = psum[nt];
            t += __shfl_xor(t, 16);
            t += __shfl_xor(t, 32);
            rsum[nt] = __builtin_amdgcn_rcpf(t);   // 1/sum for token nt*16+l15
        }

        // PV: oacc[l-tile] over 4 k-chunks of 32
        f32x4 oacc[4] = {};
#pragma unroll
        for (int ch = 0; ch < 4; ++ch) {
            bf16x8 vb = *(const bf16x8*)&vbufT[((size_t)c * 128 + h * 16 + l15) * 128 + ch * 32 + g * 8];
#pragma unroll
            for (int mt = 0; mt < 4; ++mt) {
                int l = mt * 16 + l15;
                bf16x8 pa = *(const bf16x8*)(Pb + l * 256 + ((ch * 64 + g * 16) ^ swz));
                oacc[mt] = __builtin_amdgcn_mfma_f32_16x16x32_bf16(pa, vb, oacc[mt], 0, 0, 0);
            }
        }
        // epilogue: out[l][d], col d = lane&15, row l = mt*16 + 4g + r
#pragma unroll
        for (int mt = 0; mt < 4; ++mt) {
#pragma unroll
            for (int r = 0; r < 4; ++r) {
                int l = mt * 16 + g * 4 + r;
                float sc = __shfl(pr_tok, l) * __shfl(rsum[mt], g * 4 + r);
                wout[((size_t)b * 64 + l) * KP + c * 128 + h * 16 + l15] =
                    f2bf(oacc[mt][r] * sc);
            }
        }
        // fence: PV ds_reads done before next head's P ds_writes (WAR)
        __syncthreads();
    }
    // probs tail column
    if (tid < 64)
        wout[((size_t)b * 64 + tid) * KP + 4096 + c] = f2bf(pr_tok);
}

// ---------------------------------------------------------------------------
// Kernel 4a (fallback when no workspace slack): [Wo;bo] -> WoBT, after attn.
// ---------------------------------------------------------------------------
__global__ __launch_bounds__(256) void convert_wo_kernel(
    const float* __restrict__ Wo,
    const float* __restrict__ bo,
    uint16_t* __restrict__ wobt)
{
    __shared__ float tile[32][65];
    int bid = blockIdx.x;
    int kt = bid / 12;
    int nb = bid % 12;
    int t = threadIdx.x;
    {
        int rr = t >> 3;
        int c0 = (t & 7) * 8;
        int kg = kt * 32 + rr;
        const float* src = (kg < 4096 ? Wo + (size_t)kg * DLLM
                                      : bo + (size_t)(kg - 4096) * DLLM)
                           + nb * 64 + c0;
        float4 v0 = *(const float4*)src;
        float4 v1 = *(const float4*)(src + 4);
        tile[rr][c0 + 0] = v0.x; tile[rr][c0 + 1] = v0.y;
        tile[rr][c0 + 2] = v0.z; tile[rr][c0 + 3] = v0.w;
        tile[rr][c0 + 4] = v1.x; tile[rr][c0 + 5] = v1.y;
        tile[rr][c0 + 6] = v1.z; tile[rr][c0 + 7] = v1.w;
    }
    __syncthreads();
    {
        int n  = t >> 2;
        int k0 = (t & 3) * 8;
        uint4 u;
        u.x = pack2(tile[k0 + 0][n], tile[k0 + 1][n]);
        u.y = pack2(tile[k0 + 2][n], tile[k0 + 3][n]);
        u.z = pack2(tile[k0 + 4][n], tile[k0 + 5][n]);
        u.w = pack2(tile[k0 + 6][n], tile[k0 + 7][n]);
        *(uint4*)&wobt[((size_t)(nb * 64 + n)) * KP + kt * 32 + k0] = u;
    }
}

// ---------------------------------------------------------------------------
// Kernel 4b: split-K MFMA GEMM, 128x128 tile (round-12 proven body).
// ---------------------------------------------------------------------------
__global__ __launch_bounds__(256) void fgemm_splitk_kernel(
    const uint16_t* __restrict__ wout,   // A  [4096][4128] bf16
    const uint16_t* __restrict__ wobt,   // B^T [768][4128] bf16
    float* __restrict__ part)            // [2][4096][768] fp32
{
    __shared__ short As[2][4096];
    __shared__ short Bs[2][4096];

    int bid = blockIdx.x;
    int swz = (bid & 7) * 48 + (bid >> 3);   // bijective on [0,384)
    int h  = swz / 192;                       // k-half
    int rr = swz - h * 192;
    int mb = rr / 6;                          // 0..31
    int nb = rr - mb * 6;                     // 0..5

    int tid  = threadIdx.x;
    int lane = tid & 63;
    int w    = tid >> 6;
    int wr   = w >> 1;
    int wc   = w & 1;

    int sg = tid >> 6;
    int skp = (tid >> 4) & 3;
    int sr = tid & 15;
    const uint16_t* aptr = wout + ((size_t)(mb * 128 + sg * 16 + sr)) * KP + h * 2048 + skp * 8;
    const uint16_t* bptr = wobt + ((size_t)(nb * 128 + sg * 16 + sr)) * KP + h * 2048 + skp * 8;

    short* adst[2] = { &As[0][w * 512], &As[1][w * 512] };
    short* bdst[2] = { &Bs[0][w * 512], &Bs[1][w * 512] };

    int nkt = h ? 65 : 64;

    f32x4 acc[4][4] = {};

    gload_lds16(aptr, adst[0]);
    gload_lds16(aptr + (size_t)64 * KP, adst[0] + 2048);
    gload_lds16(bptr, bdst[0]);
    gload_lds16(bptr + (size_t)64 * KP, bdst[0] + 2048);
    __syncthreads();

    int cur = 0;
    for (int kt = 0; kt < nkt; ++kt) {
        if (kt + 1 < nkt) {
            const uint16_t* ap = aptr + (size_t)(kt + 1) * 32;
            const uint16_t* bp = bptr + (size_t)(kt + 1) * 32;
            gload_lds16(ap, adst[cur ^ 1]);
            gload_lds16(ap + (size_t)64 * KP, adst[cur ^ 1] + 2048);
            gload_lds16(bp, bdst[cur ^ 1]);
            gload_lds16(bp + (size_t)64 * KP, bdst[cur ^ 1] + 2048);
        }
        const short* Ab = As[cur];
        const short* Bb = Bs[cur];
        bf16x8 av[4], bv[4];
#pragma unroll
        for (int m = 0; m < 4; ++m)
            av[m] = *(const bf16x8*)(Ab + (wr * 4 + m) * 512 + lane * 8);
#pragma unroll
        for (int n = 0; n < 4; ++n)
            bv[n] = *(const bf16x8*)(Bb + (wc * 4 + n) * 512 + lane * 8);
#pragma unroll
        for (int m = 0; m < 4; ++m)
#pragma unroll
            for (int n = 0; n < 4; ++n)
                acc[m][n] = __builtin_amdgcn_mfma_f32_16x16x32_bf16(av[m], bv[n], acc[m][n], 0, 0, 0);
        __syncthreads();
        cur ^= 1;
    }

    float* P = part + (size_t)h * (4096 * 768);
    int mbase = mb * 128 + wr * 64 + (lane >> 4) * 4;
    int nbase = nb * 128 + wc * 64 + (lane & 15);
#pragma unroll
    for (int m = 0; m < 4; ++m)
#pragma unroll
        for (int n = 0; n < 4; ++n)
#pragma unroll
            for (int r = 0; r < 4; ++r)
                P[(size_t)(mbase + m * 16 + r) * DLLM + nbase + n * 16] =
                    acc[m][n][r];
}

// ---------------------------------------------------------------------------
// Kernel 4c: reduce the two K-half partials into the fp32 output.
// ---------------------------------------------------------------------------
__global__ __launch_bounds__(256) void reduce_out_kernel(
    const float* __restrict__ part,
    float* __restrict__ out)
{
    int i = (blockIdx.x * 256 + threadIdx.x) * 4;
    float4 a = *(const float4*)(part + i);
    float4 b = *(const float4*)(part + 4096 * 768 + i);
    float4 s;
    s.x = a.x + b.x; s.y = a.y + b.y; s.z = a.z + b.z; s.w = a.w + b.w;
    *(float4*)(out + i) = s;
}

// ---------------------------------------------------------------------------
extern "C" void kernel_launch(void* const* d_in, const int* in_sizes, int n_in,
                              void* d_out, int out_size, void* d_ws, size_t ws_size,
                              hipStream_t stream) {
    const float* topk  = (const float*)d_in[0];  // (32,100,768)
    const float* ts    = (const float*)d_in[1];  // (64,64,128)
    const float* probs = (const float*)d_in[2];  // (64,64,32)
    const float* Wq    = (const float*)d_in[3];  // (32,128,129)
    const float* Wk    = (const float*)d_in[4];  // (32,128,769)
    const float* Wv    = (const float*)d_in[5];  // (32,128,769)
    const float* Wo    = (const float*)d_in[6];  // (32,128,768)
    const float* bo    = (const float*)d_in[7];  // (32,768)
    float* out = (float*)d_out;

    // workspace (uint16): kbuf | vbufT | qbuf | wout
    uint16_t* ws    = (uint16_t*)d_ws;
    uint16_t* kbuf  = ws;                          // 32*112*128  = 458752
    uint16_t* vbufT = ws + 458752;                 // 32*128*128  = 524288
    uint16_t* qbuf  = ws + 983040;                 // 32*4096*128 = 16777216
    uint16_t* wout  = ws + 983040 + 16777216;      // 4096*4128   = 16908288
    // overlays inside wout region (all dead before attn writes wout):
    uint16_t* tsbf   = wout;                       // 524288   (dead after proj)
    uint16_t* wqbf   = wout + 524288;              // 524288   (dead after proj)
    uint16_t* topkbf = wout + 1048576;             // 2457600  (dead after proj)
    uint16_t* wkbf   = wout + 1048576 + 2457600;   // 3145728  (dead after proj)
    uint16_t* wvbf   = wout + 1048576 + 2457600 + 3145728;  // 3145728, ends 9797632
    // part overlays qbuf region (dead after attn):
    float* part = (float*)(qbuf + 3170304);        // 2*4096*768 fp32 = 25.2 MB

    // wout ends at short-index 983040+16777216+16908288 = 34,668,544.
    const size_t BASE = 34668544;                  // first free short after wout
    bool slack = ws_size >= (BASE + 3170304) * sizeof(uint16_t);
    uint16_t* wobt = slack ? (ws + BASE) : qbuf;

    int nconv = slack ? 17036 : 15488;
    convert_all_kernel<<<nconv, 256, 0, stream>>>(ts, Wq, topk, Wk, Wv, Wo, bo,
                                                  tsbf, wqbf, topkbf, wkbf, wvbf, wobt);
    proj_merged_kernel<<<1280, 256, 0, stream>>>(topkbf, wkbf, wvbf, Wk, Wv,
                                                 kbuf, vbufT, tsbf, wqbf, Wq, qbuf);
    attn_mfma_kernel<<<2048, 256, 0, stream>>>(qbuf, kbuf, vbufT, probs, wout);
    if (!slack)
        convert_wo_kernel<<<1548, 256, 0, stream>>>(Wo, bo, wobt);
    fgemm_splitk_kernel<<<384, 256, 0, stream>>>(wout, wobt, part);
    reduce_out_kernel<<<3072, 256, 0, stream>>>(part, out);
}